// Round 1
// baseline (265.435 us; speedup 1.0000x reference)
//
#include <hip/hip_runtime.h>
#include <stdint.h>

#define B_    8192
#define D1_   512
#define D_    256
#define NNEG  100

typedef __attribute__((ext_vector_type(8))) short bf16x8;
typedef __attribute__((ext_vector_type(4))) float f32x4;

static __device__ __forceinline__ short f2bf(float f) {
  union { float f; unsigned u; } c; c.f = f;
  unsigned r = (c.u + 0x7FFFu + ((c.u >> 16) & 1u)) >> 16;   // RNE
  return (short)r;
}
static __device__ __forceinline__ float bf2f(short s) {
  union { unsigned u; float f; } c; c.u = ((unsigned)(unsigned short)s) << 16;
  return c.f;
}

// ---------------- K0: zero accumulators ----------------
__global__ void k0_init(float* wsf, int* hist) {
  if (threadIdx.x < 4) wsf[threadIdx.x] = 0.f;
  if (threadIdx.x >= 4 && threadIdx.x < 8) hist[threadIdx.x - 4] = 0;
}

// ---------------- K1: mse partial + domain histogram ----------------
__global__ __launch_bounds__(256) void k1_small(const float* __restrict__ yp,
                                                const float* __restrict__ yt,
                                                const int* __restrict__ tag,
                                                float* wsf, int* hist) {
  int t = blockIdx.x * 256 + threadIdx.x;   // exactly 8192 threads
  int lane = threadIdx.x & 63, wv = threadIdx.x >> 6;
  __shared__ float lsum[4];
  __shared__ int lh[4];
  if (threadIdx.x < 4) lh[threadIdx.x] = 0;
  __syncthreads();
  float d = fabsf(yp[t] - yt[t]);
  atomicAdd(&lh[tag[t]], 1);
  #pragma unroll
  for (int off = 32; off; off >>= 1) d += __shfl_down(d, off);
  if (lane == 0) lsum[wv] = d;
  __syncthreads();
  if (threadIdx.x == 0) atomicAdd(&wsf[0], lsum[0] + lsum[1] + lsum[2] + lsum[3]);
  if (threadIdx.x < 4) atomicAdd(&hist[threadIdx.x], lh[threadIdx.x]);
}

// ---------------- K2: W -> Wt (bf16, transposed [256][512]) + ||W||^2 ----------------
__global__ __launch_bounds__(256) void k2_wt(const float* __restrict__ W,
                                             short* __restrict__ Wt, float* wsf) {
  int t = blockIdx.x * 256 + threadIdx.x;   // exactly 131072 threads
  int k = t >> 8, n = t & 255;
  float w = W[t];
  Wt[n * 512 + k] = f2bf(w);
  float s = w * w;
  int lane = threadIdx.x & 63, wv = threadIdx.x >> 6;
  __shared__ float ls[4];
  #pragma unroll
  for (int off = 32; off; off >>= 1) s += __shfl_down(s, off);
  if (lane == 0) ls[wv] = s;
  __syncthreads();
  if (threadIdx.x == 0) atomicAdd(&wsf[1], ls[0] + ls[1] + ls[2] + ls[3]);
}

// ---------------- K3: phi = (mixup(e1)) @ W, bf16 MFMA, LDS-free ----------------
// grid 256 blocks x 512 thr (8 waves). Block: rows [bm0, bm0+32), all 256 cols.
// Wave w owns cols [w*32, w*32+32). Frags loaded straight from L2-hot global.
__global__ __launch_bounds__(512) void k3_gemm(const float* __restrict__ e1,
                                               const float* __restrict__ lu,
                                               const int* __restrict__ aidx,
                                               const short* __restrict__ Wt,
                                               short* __restrict__ phi) {
  const int lane = threadIdx.x & 63;
  const int wv   = threadIdx.x >> 6;          // 0..7
  const int lo   = lane & 15, hi = lane >> 4; // frag coords
  const int bm0  = blockIdx.x * 32;

  const float* pr[2]; const float* pa[2]; float lm[2];
  #pragma unroll
  for (int mt = 0; mt < 2; ++mt) {
    int r = bm0 + mt * 16 + lo;
    lm[mt] = 0.9f + 0.1f * lu[r];
    int an = aidx[r];
    int a2 = an + (an >= r);
    pr[mt] = e1 + (long)r * D1_;
    pa[mt] = e1 + (long)a2 * D1_;
  }
  const short* wb[2];
  #pragma unroll
  for (int nt = 0; nt < 2; ++nt) {
    int n = wv * 32 + nt * 16 + lo;
    wb[nt] = Wt + n * 512 + hi * 8;
  }

  f32x4 acc[2][2] = {};
  #pragma unroll
  for (int kk = 0; kk < 16; ++kk) {
    const int k = kk * 32 + hi * 8;
    bf16x8 af[2], bfg[2];
    #pragma unroll
    for (int mt = 0; mt < 2; ++mt) {
      float xs[8], ys[8];
      *(float4*)&xs[0] = *(const float4*)(pr[mt] + k);
      *(float4*)&xs[4] = *(const float4*)(pr[mt] + k + 4);
      *(float4*)&ys[0] = *(const float4*)(pa[mt] + k);
      *(float4*)&ys[4] = *(const float4*)(pa[mt] + k + 4);
      float l = lm[mt], o = 1.f - lm[mt];
      #pragma unroll
      for (int j = 0; j < 8; ++j) af[mt][j] = f2bf(l * xs[j] + o * ys[j]);
    }
    #pragma unroll
    for (int nt = 0; nt < 2; ++nt)
      bfg[nt] = *(const bf16x8*)(wb[nt] + kk * 32);

    #pragma unroll
    for (int mt = 0; mt < 2; ++mt)
      #pragma unroll
      for (int nt = 0; nt < 2; ++nt)
        acc[mt][nt] = __builtin_amdgcn_mfma_f32_16x16x32_bf16(af[mt], bfg[nt],
                                                              acc[mt][nt], 0, 0, 0);
  }
  // C/D layout: col = lane&15, row = (lane>>4)*4 + q   [measured m89/m91]
  #pragma unroll
  for (int mt = 0; mt < 2; ++mt)
    #pragma unroll
    for (int nt = 0; nt < 2; ++nt)
      #pragma unroll
      for (int q = 0; q < 4; ++q) {
        int R  = bm0 + mt * 16 + hi * 4 + q;
        int Cc = wv * 32 + nt * 16 + lo;
        phi[R * D_ + Cc] = f2bf(acc[mt][nt][q]);
      }
}

// ---------------- K4: L_aug rows (pos + 100 gathered negatives) ----------------
// 1 wave per row b; 4 groups of 16 lanes; each group owns dot i (i=0 -> pos).
__global__ __launch_bounds__(256) void k4_neg(const short* __restrict__ phi,
                                              const float* __restrict__ e2,
                                              const int* __restrict__ nidx,
                                              float* wsf) {
  const int lane = threadIdx.x & 63;
  const int wv   = threadIdx.x >> 6;
  const int b    = blockIdx.x * 4 + wv;
  const int g    = lane >> 4, q = lane & 15;

  float ev[16];
  {
    const float* er = e2 + (long)b * D_ + q * 16;
    *(float4*)&ev[0]  = *(const float4*)(er);
    *(float4*)&ev[4]  = *(const float4*)(er + 4);
    *(float4*)&ev[8]  = *(const float4*)(er + 8);
    *(float4*)&ev[12] = *(const float4*)(er + 12);
  }

  float posv = 0.f, negs = 0.f;
  for (int i = g; i <= NNEG; i += 4) {
    int r;
    if (i == 0) r = b;
    else { int nn = nidx[b * NNEG + (i - 1)]; r = nn + (nn >= b); }
    const bf16x8* pp = (const bf16x8*)(phi + (long)r * D_ + q * 16);
    short pv[16];
    *(bf16x8*)&pv[0] = pp[0];
    *(bf16x8*)&pv[8] = pp[1];
    float s = 0.f;
    #pragma unroll
    for (int j = 0; j < 16; ++j) s += bf2f(pv[j]) * ev[j];
    s += __shfl_xor(s, 1);
    s += __shfl_xor(s, 2);
    s += __shfl_xor(s, 4);
    s += __shfl_xor(s, 8);                  // group-wide dot
    float ex = expf(1e-6f * s);
    if (i == 0) posv = ex; else negs += ex;
  }
  negs += __shfl_xor(negs, 16);
  negs += __shfl_xor(negs, 32);             // sum over the 4 groups
  posv = __shfl(posv, 0);                   // pos lives in group 0
  if (lane == 0) {
    float row = logf(posv / (1e-6f + posv + negs));
    atomicAdd(&wsf[2], row);
  }
}

// ---------------- K5: combine ----------------
__global__ void k5_fin(const float* wsf, const int* hist, float* out) {
  if (threadIdx.x == 0 && blockIdx.x == 0) {
    float mse = wsf[0] * (1.f / 8192.f);
    float reg = 1e-4f * sqrtf(wsf[1]);
    float aug = 0.1f * (-wsf[2] * (1.f / 8192.f));
    // L_supp: S==1.0f bit-exactly in fp32 (tau=1e-10; see analysis) ->
    // nom=count_diff, den=8192.0f exactly; den+1e-6f rounds to 8192.0f.
    float ss = 0.f;
    for (int t = 0; t < 4; ++t) {
      int c = hist[t];
      int cd = B_ - c;
      if (c > 0 && cd > 0)
        ss += (float)c * logf((float)cd / (8192.f + 1e-6f));
    }
    float supp = 1e-3f * (-ss * (1.f / 8192.f));
    out[0] = mse + reg + aug + supp;
  }
}

extern "C" void kernel_launch(void* const* d_in, const int* in_sizes, int n_in,
                              void* d_out, int out_size, void* d_ws, size_t ws_size,
                              hipStream_t stream) {
  const float* e1  = (const float*)d_in[0];
  const float* e2  = (const float*)d_in[1];
  const float* yp  = (const float*)d_in[2];
  const float* yt  = (const float*)d_in[3];
  const float* W   = (const float*)d_in[4];
  const float* lu  = (const float*)d_in[5];
  const int*   tag = (const int*)d_in[6];
  const int*   aix = (const int*)d_in[7];
  const int*   nix = (const int*)d_in[8];
  float* out = (float*)d_out;

  char* ws   = (char*)d_ws;
  float* wsf = (float*)ws;                      // [0]=mse [1]=reg [2]=aug
  int*   hist = (int*)(ws + 16);                // 4 bins
  short* Wt  = (short*)(ws + 256);              // 256x512 bf16 = 256 KB
  short* phi = (short*)(ws + 256 + 262144);     // 8192x256 bf16 = 4 MB

  k0_init<<<1, 64, 0, stream>>>(wsf, hist);
  k1_small<<<32, 256, 0, stream>>>(yp, yt, tag, wsf, hist);
  k2_wt<<<512, 256, 0, stream>>>(W, Wt, wsf);
  k3_gemm<<<256, 512, 0, stream>>>(e1, lu, aix, Wt, phi);
  k4_neg<<<2048, 256, 0, stream>>>(phi, e2, nix, wsf);
  k5_fin<<<1, 64, 0, stream>>>(wsf, hist, out);
}

// Round 2
// 152.675 us; speedup vs baseline: 1.7386x; 1.7386x over previous
//
#include <hip/hip_runtime.h>
#include <stdint.h>

#define B_    8192
#define D1_   512
#define D_    256
#define NNEG  100

typedef __attribute__((ext_vector_type(8))) short bf16x8;
typedef __attribute__((ext_vector_type(4))) short bf16x4;
typedef __attribute__((ext_vector_type(4))) float f32x4;

static __device__ __forceinline__ short f2bf(float f) {
  union { float f; unsigned u; } c; c.f = f;
  unsigned r = (c.u + 0x7FFFu + ((c.u >> 16) & 1u)) >> 16;   // RNE
  return (short)r;
}
static __device__ __forceinline__ float bf2f(short s) {
  union { unsigned u; float f; } c; c.u = ((unsigned)(unsigned short)s) << 16;
  return c.f;
}

// ---------------- K0: zero accumulators ----------------
__global__ void k0_init(float* wsf, int* hist) {
  if (threadIdx.x < 4) wsf[threadIdx.x] = 0.f;
  if (threadIdx.x >= 4 && threadIdx.x < 8) hist[threadIdx.x - 4] = 0;
}

// ---------------- KA: fused  W->Wt(bf16,T) + ||W||^2  +  mse + domain hist ----
// grid 512 x 256 = 131072 threads (== |W|); threads t<8192 also do y/tag work.
__global__ __launch_bounds__(256) void kA_pre(const float* __restrict__ W,
                                              short* __restrict__ Wt,
                                              const float* __restrict__ yp,
                                              const float* __restrict__ yt,
                                              const int* __restrict__ tag,
                                              float* wsf, int* hist) {
  const int t = blockIdx.x * 256 + threadIdx.x;
  const int lane = threadIdx.x & 63, wv = threadIdx.x >> 6;
  __shared__ float lw[4], lm[4];
  __shared__ int lh[4];
  if (threadIdx.x < 4) lh[threadIdx.x] = 0;
  __syncthreads();

  const int k = t >> 8, n = t & 255;
  float w = W[t];
  Wt[n * 512 + k] = f2bf(w);
  float s = w * w;

  float d = 0.f;
  if (t < 8192) {
    d = fabsf(yp[t] - yt[t]);
    atomicAdd(&lh[tag[t]], 1);
  }
  #pragma unroll
  for (int off = 32; off; off >>= 1) {
    s += __shfl_down(s, off);
    d += __shfl_down(d, off);
  }
  if (lane == 0) { lw[wv] = s; lm[wv] = d; }
  __syncthreads();
  if (threadIdx.x == 0) {
    atomicAdd(&wsf[1], lw[0] + lw[1] + lw[2] + lw[3]);
    float dm = lm[0] + lm[1] + lm[2] + lm[3];
    if (dm != 0.f || blockIdx.x < 32) atomicAdd(&wsf[0], dm);
  }
  if (threadIdx.x < 4 && lh[threadIdx.x] != 0)
    atomicAdd(&hist[threadIdx.x], lh[threadIdx.x]);
}

// ---------------- K3: phi = mixup(e1) @ W  (bf16 MFMA, LDS-staged A) ----------
// 512 blocks x 1024 thr (16 waves). Block: 16 rows x all 256 cols.
// Wave w computes the 16x16 tile at cols [w*16, w*16+16).
__global__ __launch_bounds__(1024) void k3_gemm(const float* __restrict__ e1,
                                                const float* __restrict__ lu,
                                                const int* __restrict__ aidx,
                                                const short* __restrict__ Wt,
                                                short* __restrict__ phi) {
  __shared__ short As[16 * 512];            // 16 KB, XOR-swizzled
  char* asb = (char*)As;
  const int t = threadIdx.x;
  const int bm0 = blockIdx.x * 16;

  // --- stage mixed-up A tile (bf16) ---
  {
    const int r = t >> 6;                   // 0..15 (== wave id)
    const int row = bm0 + r;
    const float lmv = 0.9f + 0.1f * lu[row];
    const float omv = 1.f - lmv;
    int an = aidx[row];
    int a2 = an + (an >= row);
    const float* px = e1 + (long)row * D1_;
    const float* py = e1 + (long)a2 * D1_;
    const int c0 = (t & 63) * 4;            // elem col
    #pragma unroll
    for (int j = 0; j < 2; ++j) {
      const int c = c0 + j * 256;
      float4 x = *(const float4*)(px + c);
      float4 y = *(const float4*)(py + c);
      bf16x4 o;
      o[0] = f2bf(lmv * x.x + omv * y.x);
      o[1] = f2bf(lmv * x.y + omv * y.y);
      o[2] = f2bf(lmv * x.z + omv * y.z);
      o[3] = f2bf(lmv * x.w + omv * y.w);
      *(bf16x4*)(asb + r * 1024 + ((c * 2) ^ ((r & 7) << 4))) = o;
    }
  }
  __syncthreads();

  // --- MFMA ---
  const int lane = t & 63, wv = t >> 6;
  const int lo = lane & 15, hi = lane >> 4;
  const short* wb = Wt + (wv * 16 + lo) * 512;

  f32x4 acc = {};
  #pragma unroll
  for (int kk = 0; kk < 16; ++kk) {
    bf16x8 a = *(const bf16x8*)(asb + lo * 1024 + ((kk * 64 + hi * 16) ^ ((lo & 7) << 4)));
    bf16x8 b = *(const bf16x8*)(wb + kk * 32 + hi * 8);
    acc = __builtin_amdgcn_mfma_f32_16x16x32_bf16(a, b, acc, 0, 0, 0);
  }
  // C/D layout: col = lane&15, row = (lane>>4)*4 + q
  #pragma unroll
  for (int q = 0; q < 4; ++q) {
    int R = bm0 + hi * 4 + q;
    phi[R * D_ + wv * 16 + lo] = f2bf(acc[q]);
  }
}

// ---------------- K4: L_aug rows, linearized exp -------------------------------
// sum_i exp(tau*s_i) == 100 + tau*dot(sum_i phi[r_i], e2[b])  (exact at fp32 lsb)
// 1 wave per row; two 32-lane halves each accumulate 50 gathered phi rows.
__global__ __launch_bounds__(256) void k4_neg(const short* __restrict__ phi,
                                              const float* __restrict__ e2,
                                              const int* __restrict__ nidx,
                                              float* wsf) {
  const int lane = threadIdx.x & 63;
  const int wv   = threadIdx.x >> 6;
  const int b    = blockIdx.x * 4 + wv;
  const int h    = lane >> 5;              // half: even/odd negatives
  const int q    = lane & 31;              // elem chunk: q*8 .. q*8+8

  const int* nrow = nidx + b * NNEG;
  float acc[8] = {0.f, 0.f, 0.f, 0.f, 0.f, 0.f, 0.f, 0.f};

  #pragma unroll 1
  for (int it = 0; it < 10; ++it) {
    bf16x8 v[5];
    #pragma unroll
    for (int u = 0; u < 5; ++u) {
      int i = (it * 5 + u) * 2 + h;
      int nn = nrow[i];
      int r = nn + (nn >= b);
      v[u] = *(const bf16x8*)(phi + (long)r * D_ + q * 8);
    }
    #pragma unroll
    for (int u = 0; u < 5; ++u)
      #pragma unroll
      for (int j = 0; j < 8; ++j)
        acc[j] += bf2f(v[u][j]);
  }

  // dots with e2[b] (neg-sum and positive), then wave reduce
  const float* er = e2 + (long)b * D_ + q * 8;
  float ev[8];
  *(float4*)&ev[0] = *(const float4*)(er);
  *(float4*)&ev[4] = *(const float4*)(er + 4);
  bf16x8 pb = *(const bf16x8*)(phi + (long)b * D_ + q * 8);

  float sneg = 0.f, spos = 0.f;
  #pragma unroll
  for (int j = 0; j < 8; ++j) {
    sneg += acc[j] * ev[j];
    spos += bf2f(pb[j]) * ev[j];
  }
  #pragma unroll
  for (int off = 1; off <= 32; off <<= 1) {
    sneg += __shfl_xor(sneg, off);
    spos += __shfl_xor(spos, off);
  }

  __shared__ float lrow[4];
  if (lane == 0) {
    spos *= 0.5f;                          // both halves computed the pos dot
    float pos  = 1.f + 1e-6f * spos;
    float negs = 100.f + 1e-6f * sneg;
    lrow[wv] = logf(pos / (1e-6f + pos + negs));
  }
  __syncthreads();
  if (threadIdx.x == 0)
    atomicAdd(&wsf[2], lrow[0] + lrow[1] + lrow[2] + lrow[3]);
}

// ---------------- K5: combine ----------------
__global__ void k5_fin(const float* wsf, const int* hist, float* out) {
  if (threadIdx.x == 0 && blockIdx.x == 0) {
    float mse = wsf[0] * (1.f / 8192.f);
    float reg = 1e-4f * sqrtf(wsf[1]);
    float aug = 0.1f * (-wsf[2] * (1.f / 8192.f));
    // L_supp: S==1.0f bit-exactly in fp32 (tau=1e-10) -> nom=count_diff,
    // den=8192.0f exactly; den+1e-6f rounds to 8192.0f.
    float ss = 0.f;
    for (int t = 0; t < 4; ++t) {
      int c = hist[t];
      int cd = B_ - c;
      if (c > 0 && cd > 0)
        ss += (float)c * logf((float)cd / (8192.f + 1e-6f));
    }
    float supp = 1e-3f * (-ss * (1.f / 8192.f));
    out[0] = mse + reg + aug + supp;
  }
}

extern "C" void kernel_launch(void* const* d_in, const int* in_sizes, int n_in,
                              void* d_out, int out_size, void* d_ws, size_t ws_size,
                              hipStream_t stream) {
  const float* e1  = (const float*)d_in[0];
  const float* e2  = (const float*)d_in[1];
  const float* yp  = (const float*)d_in[2];
  const float* yt  = (const float*)d_in[3];
  const float* W   = (const float*)d_in[4];
  const float* lu  = (const float*)d_in[5];
  const int*   tag = (const int*)d_in[6];
  const int*   aix = (const int*)d_in[7];
  const int*   nix = (const int*)d_in[8];
  float* out = (float*)d_out;

  char* ws    = (char*)d_ws;
  float* wsf  = (float*)ws;                     // [0]=mse [1]=w2 [2]=aug
  int*   hist = (int*)(ws + 16);                // 4 bins
  short* Wt   = (short*)(ws + 256);             // 256x512 bf16 = 256 KB
  short* phi  = (short*)(ws + 256 + 262144);    // 8192x256 bf16 = 4 MB

  k0_init<<<1, 64, 0, stream>>>(wsf, hist);
  kA_pre<<<512, 256, 0, stream>>>(W, Wt, yp, yt, tag, wsf, hist);
  k3_gemm<<<512, 1024, 0, stream>>>(e1, lu, aix, Wt, phi);
  k4_neg<<<2048, 256, 0, stream>>>(phi, e2, nix, wsf);
  k5_fin<<<1, 64, 0, stream>>>(wsf, hist, out);
}